// Round 5
// baseline (188.642 us; speedup 1.0000x reference)
//
#include <hip/hip_runtime.h>

typedef float  float4_t __attribute__((ext_vector_type(4)));
typedef unsigned int uint4_t __attribute__((ext_vector_type(4)));
typedef short  bf16x8  __attribute__((ext_vector_type(8)));
typedef float  f32x4   __attribute__((ext_vector_type(4)));

#define A_N    256
#define NVIEW  8
#define FEAT   256
#define BANK   2048
#define NROWS  2048       // A_N * NVIEW
#define BM     128
#define BN     128
#define BK     64
#define NCT    288        // column tiles
#define NCTG   32         // ct groups (one per persistent block column-slot)
#define CTS_PER 9         // NCT / NCTG
#define NSTEP  36         // CTS_PER * 4 kt-steps
#define INV_TEMP 10.0f
#define A_CHUNKS 65536        // 2048*256/8 bf16 chunks of 8
#define B_CHUNKS 1179648      // 36864*256/8
#define TOT_CHUNKS (A_CHUNKS + B_CHUNKS)

typedef unsigned int __attribute__((address_space(1))) guint;
typedef unsigned int __attribute__((address_space(3))) luint;

// round-to-nearest-even f32 -> bf16, two at a time packed into a uint
__device__ inline unsigned int pack_bf16x2(float lo, float hi) {
    unsigned int ulo = __builtin_bit_cast(unsigned int, lo);
    unsigned int uhi = __builtin_bit_cast(unsigned int, hi);
    unsigned int rl = 0x7FFFu + ((ulo >> 16) & 1u);
    unsigned int rh = 0x7FFFu + ((uhi >> 16) & 1u);
    return ((ulo + rl) >> 16) | ((uhi + rh) & 0xFFFF0000u);
}

__global__ __launch_bounds__(256) void zero_kernel(float* __restrict__ out) {
    if (threadIdx.x == 0 && blockIdx.x == 0) out[0] = 0.0f;
}

// Pass 0: convert fp32 -> bf16 ONCE, pre-packed in MFMA fragment order so that
// pass1 can DMA it linearly into LDS with global_load_lds (16B/lane).
// Tile = 128 rows x 64 k, 8192 bf16 = 1024 chunks of 8.
__global__ __launch_bounds__(256) void pass0_pack(
    const float* __restrict__ X,    // X_anchor [256][8][256]
    const float* __restrict__ Q,    // queue [19][2048][256]
    unsigned short* __restrict__ Abuf,
    unsigned short* __restrict__ Bbuf)
{
    const int cid = blockIdx.x * 256 + threadIdx.x;
    if (cid >= TOT_CHUNKS) return;
    const int ch = cid & 1023;
    const int frag = ch >> 6, ln = ch & 63;
    const int rf = frag >> 1, kf = frag & 1;
    const int rloc = (rf << 4) | (ln & 15);
    const int kloc = (kf << 5) | ((ln >> 4) << 3);
    const float* src;
    unsigned short* dst;
    if (cid < A_CHUNKS) {
        const int tileid = cid >> 10;               // rt*4 + kt
        const int rt = tileid >> 2, kt = tileid & 3;
        const int r = rt * BM + rloc;               // anchor_feature row: v*256+a
        const int k = kt * BK + kloc;
        src = X + (((size_t)((r & 255) * NVIEW + (r >> 8))) << 8) + k;
        dst = Abuf + ((size_t)cid << 3);
    } else {
        const int bcid = cid - A_CHUNKS;
        const int tileid = bcid >> 10;              // ct*4 + kt
        const int ct = tileid >> 2, kt = tileid & 3;
        const int j = ct * BN + rloc;               // contrast col (class 0 skipped)
        const int k = kt * BK + kloc;
        src = Q + (((size_t)(BANK + j)) << 8) + k;
        dst = Bbuf + ((size_t)bcid << 3);
    }
    float4_t v0 = *(const float4_t*)src;
    float4_t v1 = *(const float4_t*)(src + 4);
    uint4_t p = { pack_bf16x2(v0.x, v0.y), pack_bf16x2(v0.z, v0.w),
                  pack_bf16x2(v1.x, v1.y), pack_bf16x2(v1.z, v1.w) };
    *(uint4_t*)dst = p;
}

// Pass 1: PERSISTENT blocks (512 = 2/CU). Block = 128-row strip x 9 col-tiles.
// 36-step double-buffered stage-ahead pipeline; exp row-sums accumulate in
// registers across the ct loop; part2 written once per block at the end.
__global__ __launch_bounds__(256) void pass1_gemm(
    const unsigned short* __restrict__ Abuf,
    const unsigned short* __restrict__ Bbuf,
    const int*   __restrict__ y,
    float* __restrict__ part2,  // [NCTG*2][NROWS]
    float* __restrict__ pos)    // [NROWS][BANK]
{
    __shared__ __align__(16) unsigned short lA[2][8192];   // 2 x 16 KB
    __shared__ __align__(16) unsigned short lB[2][8192];

    const int bid = blockIdx.x;
    const int rt  = bid >> 5;                           // [0,16) row strip
    const int ctg = (bid & 7) * 4 + ((bid >> 3) & 3);   // [0,32) XCD-grouped
    const int ctFirst = ctg * CTS_PER;

    const int t    = threadIdx.x;
    const int lane = t & 63;
    const int w    = t >> 6;
    const int wr   = w >> 1, wc = w & 1;    // 2x2 waves, each 64x64
    const int g    = lane >> 4;

    // per-thread row classes (rows are block-stationary)
    int yv[16];
    #pragma unroll
    for (int mi = 0; mi < 4; ++mi)
        #pragma unroll
        for (int rj = 0; rj < 4; ++rj) {
            const int r = rt * BM + wr * 64 + mi * 16 + g * 4 + rj;
            yv[mi * 4 + rj] = y[r & 255];
        }

    f32x4 acc[4][4] = {};
    float rsv[16] = {};

    auto STAGE = [&](int buf, int s) {
        const int ct = ctFirst + (s >> 2), kt = s & 3;
        const unsigned short* Ab = Abuf + (((size_t)(rt * 4 + kt)) << 13);
        const unsigned short* Bb = Bbuf + (((size_t)(ct * 4 + kt)) << 13);
        #pragma unroll
        for (int i = 0; i < 4; ++i) {
            const int cb = (w * 4 + i) << 6;     // wave-uniform chunk base
            __builtin_amdgcn_global_load_lds((const guint*)(Ab + ((size_t)(cb + lane) << 3)),
                                             (luint*)&lA[buf][(size_t)cb << 3], 16, 0, 0);
            __builtin_amdgcn_global_load_lds((const guint*)(Bb + ((size_t)(cb + lane) << 3)),
                                             (luint*)&lB[buf][(size_t)cb << 3], 16, 0, 0);
        }
    };

    STAGE(0, 0);
    __syncthreads();

    int cur = 0;
    for (int s = 0; s < NSTEP; ++s) {
        if (s + 1 < NSTEP) STAGE(cur ^ 1, s + 1);   // loads fly under compute

        #pragma unroll
        for (int ks = 0; ks < 2; ++ks) {
            bf16x8 af[4], bfv[4];
            #pragma unroll
            for (int mi = 0; mi < 4; ++mi)
                af[mi] = *(const bf16x8*)&lA[cur][((((wr * 4 + mi) << 1) | ks) << 9) + lane * 8];
            #pragma unroll
            for (int ni = 0; ni < 4; ++ni)
                bfv[ni] = *(const bf16x8*)&lB[cur][((((wc * 4 + ni) << 1) | ks) << 9) + lane * 8];
            #pragma unroll
            for (int mi = 0; mi < 4; ++mi)
                #pragma unroll
                for (int ni = 0; ni < 4; ++ni)
                    acc[mi][ni] = __builtin_amdgcn_mfma_f32_16x16x32_bf16(af[mi], bfv[ni], acc[mi][ni], 0, 0, 0);
        }

        if ((s & 3) == 3) {
            // ---- per-ct mini-epilogue: exp + register accumulate + pos stores ----
            const int ct = ctFirst + (s >> 2);
            const int cj = (ct >> 4) + 1;           // class of this col tile (1..18)
            const int colbase = ct * BN + wc * 64 + (lane & 15);
            #pragma unroll
            for (int mi = 0; mi < 4; ++mi) {
                #pragma unroll
                for (int rj = 0; rj < 4; ++rj) {
                    const int r = rt * BM + wr * 64 + mi * 16 + g * 4 + rj;
                    const bool isPos = (yv[mi * 4 + rj] == cj);
                    float rs = 0.0f;
                    #pragma unroll
                    for (int ni = 0; ni < 4; ++ni) {
                        const float lv = acc[mi][ni][rj] * INV_TEMP;
                        rs += __expf(lv);
                        if (isPos) pos[(size_t)r * BANK + ((colbase + ni * 16) & (BANK - 1))] = lv;
                    }
                    rs += __shfl_xor(rs, 1);
                    rs += __shfl_xor(rs, 2);
                    rs += __shfl_xor(rs, 4);
                    rs += __shfl_xor(rs, 8);
                    rsv[mi * 4 + rj] += rs;
                }
            }
            #pragma unroll
            for (int mi = 0; mi < 4; ++mi)
                #pragma unroll
                for (int ni = 0; ni < 4; ++ni)
                    acc[mi][ni] = (f32x4){0.0f, 0.0f, 0.0f, 0.0f};
        }

        __syncthreads();
        cur ^= 1;
    }

    // ---- block epilogue: per-wave row partials (leader lanes, 4 active/store) ----
    float* p2 = part2 + ((size_t)(ctg * 2 + wc)) * NROWS + rt * BM + wr * 64;
    #pragma unroll
    for (int mi = 0; mi < 4; ++mi)
        #pragma unroll
        for (int rj = 0; rj < 4; ++rj)
            if ((lane & 15) == 0) p2[mi * 16 + g * 4 + rj] = rsv[mi * 4 + rj];
}

// Pass 3: per-row finish. S_all = sum of 64 part2 entries; N = S_all - posExpSum + 2048.
// P = sum over positives of (l - log(exp(l)+N)), excluding diagonal for class-1 rows.
__global__ __launch_bounds__(256) void pass3_kernel(
    const int* __restrict__ y, const float* __restrict__ part2,
    const float* __restrict__ pos, float* __restrict__ out)
{
    __shared__ float sh[12];
    const int r = blockIdx.x;
    const int t = threadIdx.x;
    const int c = y[r & 255];
    const float4_t* row4 = (const float4_t*)(pos + (size_t)r * BANK);
    float4_t va = row4[t];
    float4_t vb = row4[t + 256];
    float l[8] = { va.x, va.y, va.z, va.w, vb.x, vb.y, vb.z, vb.w };
    float e[8];
    float eSum = 0.0f;
    #pragma unroll
    for (int i = 0; i < 8; ++i) { e[i] = __expf(l[i]); eSum += e[i]; }
    float sa = 0.0f;
    if (t < 64) sa = part2[(size_t)t * NROWS + r];
    #pragma unroll
    for (int m = 1; m < 64; m <<= 1) {
        eSum += __shfl_xor(eSum, m);
        sa   += __shfl_xor(sa, m);
    }
    const int w = t >> 6;
    if ((t & 63) == 0) { sh[w] = eSum; sh[4 + w] = sa; }
    __syncthreads();
    const float eTot  = sh[0] + sh[1] + sh[2] + sh[3];
    const float saTot = sh[4] + sh[5] + sh[6] + sh[7];
    const float N = saTot - eTot + (float)BANK;

    float P = 0.0f;
    #pragma unroll
    for (int i = 0; i < 8; ++i) {
        const int m = (i < 4) ? (4 * t + i) : (1024 + 4 * t + (i - 4));
        const bool skip = (c == 1) && (m == r);
        if (!skip) P += l[i] - __logf(e[i] + N);
    }
    #pragma unroll
    for (int m = 1; m < 64; m <<= 1) P += __shfl_xor(P, m);
    if ((t & 63) == 0) sh[8 + w] = P;
    __syncthreads();
    if (t == 0) {
        const float Ptot = sh[8] + sh[9] + sh[10] + sh[11];
        const float denom = (c == 1) ? (float)(BANK - 1) : (float)BANK;
        atomicAdd(out, (-Ptot / denom) * (1.0f / (float)NROWS));
    }
}

extern "C" void kernel_launch(void* const* d_in, const int* in_sizes, int n_in,
                              void* d_out, int out_size, void* d_ws, size_t ws_size,
                              hipStream_t stream) {
    const float* X = (const float*)d_in[0];
    const int*   y = (const int*)d_in[1];
    const float* Q = (const float*)d_in[2];
    float* out   = (float*)d_out;
    float* pos   = (float*)d_ws;                                 // 2048*2048 f32 (16.8 MB)
    float* part2 = pos + (size_t)NROWS * BANK;                   // 64*2048 f32 (512 KB)
    unsigned short* Abuf = (unsigned short*)(part2 + (size_t)NCTG * 2 * NROWS); // 1 MB
    unsigned short* Bbuf = Abuf + ((size_t)A_CHUNKS << 3);                      // 18.9 MB

    zero_kernel<<<dim3(1), dim3(256), 0, stream>>>(out);
    pass0_pack<<<dim3(TOT_CHUNKS / 256), dim3(256), 0, stream>>>(X, Q, Abuf, Bbuf);
    pass1_gemm<<<dim3(512), dim3(256), 0, stream>>>(Abuf, Bbuf, y, part2, pos);
    pass3_kernel<<<dim3(NROWS), dim3(256), 0, stream>>>(y, part2, pos, out);
}

// Round 6
// 149.805 us; speedup vs baseline: 1.2593x; 1.2593x over previous
//
#include <hip/hip_runtime.h>

typedef float  float4_t __attribute__((ext_vector_type(4)));
typedef unsigned int uint4_t __attribute__((ext_vector_type(4)));
typedef short  bf16x8  __attribute__((ext_vector_type(8)));
typedef float  f32x4   __attribute__((ext_vector_type(4)));

#define FEAT   256
#define BANK   2048
#define NROWS  2048       // 256 anchors * 8 views
#define NCOLS  36864      // 18 real classes * 2048
#define NPANEL 576        // NCOLS / 64
#define NGRP   64         // col groups (panels per group = 9)
#define PPG    9
#define NSTRIP 8          // 2048 / 256 rows per block
#define INV_TEMP 10.0f
#define A_CHUNKS 65536        // 2048*256/8
#define B_CHUNKS 1179648      // 36864*256/8
#define TOT_CHUNKS (A_CHUNKS + B_CHUNKS)

typedef unsigned int __attribute__((address_space(1))) guint;
typedef unsigned int __attribute__((address_space(3))) luint;

// round-to-nearest-even f32 -> bf16, two at a time packed into a uint
__device__ inline unsigned int pack_bf16x2(float lo, float hi) {
    unsigned int ulo = __builtin_bit_cast(unsigned int, lo);
    unsigned int uhi = __builtin_bit_cast(unsigned int, hi);
    unsigned int rl = 0x7FFFu + ((ulo >> 16) & 1u);
    unsigned int rh = 0x7FFFu + ((uhi >> 16) & 1u);
    return ((ulo + rl) >> 16) | ((uhi + rh) & 0xFFFF0000u);
}

// Pass 0: convert fp32 -> bf16 ONCE into MFMA fragment order.
// A layout: chunk = (((s*4+w)*4+mi)*8+ks)*64 + lane ; row = s*256+w*64+mi*16+(lane&15),
//           k = ks*32+(lane>>4)*8.  (wave-register A fragments, coalesced 16B loads)
// B layout: chunk = (p*32 + ks*4+ni)*64 + lane ; col = p*64+ni*16+(lane&15), same k map.
__global__ __launch_bounds__(256) void pass0_pack(
    const float* __restrict__ X,    // X_anchor [256][8][256]
    const float* __restrict__ Q,    // queue [19][2048][256]
    unsigned short* __restrict__ Abuf,
    unsigned short* __restrict__ Bbuf,
    float* __restrict__ out)
{
    const int cid = blockIdx.x * 256 + threadIdx.x;
    if (cid == 0) out[0] = 0.0f;                 // fold zero_kernel in
    if (cid >= TOT_CHUNKS) return;
    const int lane = cid & 63;
    const int rsub = lane & 15, ksub = lane >> 4;
    const float* src;
    unsigned short* dst;
    if (cid < A_CHUNKS) {
        const int ks = (cid >> 6) & 7;
        const int mi = (cid >> 9) & 3;
        const int w  = (cid >> 11) & 3;
        const int s  = cid >> 13;
        const int r  = s * 256 + w * 64 + mi * 16 + rsub;   // anchor row = v*256+a
        const int k  = ks * 32 + ksub * 8;
        src = X + ((size_t)((r & 255) * 8 + (r >> 8))) * FEAT + k;
        dst = Abuf + ((size_t)cid << 3);
    } else {
        const int bcid = cid - A_CHUNKS;
        const int f  = (bcid >> 6) & 31;
        const int ni = f & 3, ks = f >> 2;
        const int p  = bcid >> 11;
        const int col = p * 64 + ni * 16 + rsub;            // class 0 skipped below
        const int k   = ks * 32 + ksub * 8;
        src = Q + ((size_t)(BANK + col)) * FEAT + k;
        dst = Bbuf + ((size_t)bcid << 3);
    }
    float4_t v0 = *(const float4_t*)src;
    float4_t v1 = *(const float4_t*)(src + 4);
    uint4_t p = { pack_bf16x2(v0.x, v0.y), pack_bf16x2(v0.z, v0.w),
                  pack_bf16x2(v1.x, v1.y), pack_bf16x2(v1.z, v1.w) };
    *(uint4_t*)dst = p;
}

// Pass 1: A-in-registers GEMM. Block = 256 rows (4 waves x 64 rows), 9 B-panels
// of 64 cols x K=256 staged via global_load_lds, double-buffered, counted-vmcnt
// pipeline (never vmcnt(0) mid-loop). Exp row-sums accumulate per-lane in regs.
__global__ __launch_bounds__(256, 2) void pass1_gemm(
    const unsigned short* __restrict__ Abuf,
    const unsigned short* __restrict__ Bbuf,
    const int*   __restrict__ y,
    float* __restrict__ part,   // [NROWS][NGRP]
    float* __restrict__ pos)    // [NROWS][BANK]
{
    __shared__ __align__(16) unsigned short lB[2][16384];   // 2 x 32 KB

    const int bid = blockIdx.x;
    const int s   = bid >> 6;          // row strip   (bid%8 == g%8 -> XCD locality on B)
    const int g   = bid & 63;          // col group
    const int t    = threadIdx.x;
    const int lane = t & 63;
    const int w    = t >> 6;
    const int rsub = lane >> 4;        // 0..3

    // ---- A fragments for this wave's 64 rows, kept in registers ----
    bf16x8 af[4][8];
    {
        const bf16x8* Asrc = (const bf16x8*)Abuf + ((size_t)(s * 4 + w) * 2048 + lane);
        #pragma unroll
        for (int mi = 0; mi < 4; ++mi)
            #pragma unroll
            for (int ks = 0; ks < 8; ++ks)
                af[mi][ks] = Asrc[(mi * 8 + ks) * 64];
    }
    // y classes packed: ypack[mi] byte rj = y[row(mi,rj) & 255]
    unsigned int ypack[4];
    #pragma unroll
    for (int mi = 0; mi < 4; ++mi) {
        unsigned int v = 0;
        #pragma unroll
        for (int rj = 0; rj < 4; ++rj)
            v |= ((unsigned int)y[w * 64 + mi * 16 + rsub * 4 + rj]) << (rj * 8);
        ypack[mi] = v;
    }

    f32x4 acc[4][4] = {};
    float rsv[16] = {};

    const size_t pchunk0 = (size_t)(g * PPG) << 11;   // group's first panel chunk

    auto STAGE = [&](int buf, int st) {
        const unsigned short* B = Bbuf + ((pchunk0 + ((size_t)st << 11)) << 3);
        #pragma unroll
        for (int i = 0; i < 8; ++i) {
            const int cb = w * 512 + i * 64;           // wave-uniform chunk base
            __builtin_amdgcn_global_load_lds((const guint*)(B + ((size_t)(cb + lane) << 3)),
                                             (luint*)&lB[buf][(size_t)cb << 3], 16, 0, 0);
        }
    };

    STAGE(0, 0);

    int cur = 0;
    #pragma unroll 1
    for (int st = 0; st < PPG; ++st) {
        if (st + 1 < PPG) {
            STAGE(cur ^ 1, st + 1);                        // next panel: stays in flight
            asm volatile("s_waitcnt vmcnt(8)" ::: "memory");   // only CURRENT panel drained
        } else {
            asm volatile("s_waitcnt vmcnt(0)" ::: "memory");
        }
        __builtin_amdgcn_s_barrier();                      // all waves' stage(cur) landed
        asm volatile("" ::: "memory");                     // pin LDS reads below barrier

        #pragma unroll
        for (int ks = 0; ks < 8; ++ks) {
            #pragma unroll
            for (int ni = 0; ni < 4; ++ni) {
                const bf16x8 bv = *(const bf16x8*)&lB[cur][(size_t)((((ks << 2) | ni) << 6) | lane) << 3];
                acc[0][ni] = __builtin_amdgcn_mfma_f32_16x16x32_bf16(af[0][ks], bv, acc[0][ni], 0, 0, 0);
                acc[1][ni] = __builtin_amdgcn_mfma_f32_16x16x32_bf16(af[1][ks], bv, acc[1][ni], 0, 0, 0);
                acc[2][ni] = __builtin_amdgcn_mfma_f32_16x16x32_bf16(af[2][ks], bv, acc[2][ni], 0, 0, 0);
                acc[3][ni] = __builtin_amdgcn_mfma_f32_16x16x32_bf16(af[3][ks], bv, acc[3][ni], 0, 0, 0);
            }
        }
        asm volatile("s_waitcnt lgkmcnt(0)" ::: "memory"); // my ds_reads consumed
        __builtin_amdgcn_s_barrier();                      // safe to overwrite cur next iter
        asm volatile("" ::: "memory");

        // ---- per-panel epilogue (regs + global only; overlaps next stage flight) ----
        const int p  = g * PPG + st;
        const int cj = (p >> 5) + 1;
        const int cbase = ((p & 31) << 6) | (lane & 15);
        #pragma unroll
        for (int mi = 0; mi < 4; ++mi) {
            #pragma unroll
            for (int rj = 0; rj < 4; ++rj) {
                const bool isPos = (((ypack[mi] >> (rj * 8)) & 255u) == (unsigned int)cj);
                const int r = s * 256 + w * 64 + mi * 16 + rsub * 4 + rj;
                float rs = 0.0f;
                #pragma unroll
                for (int ni = 0; ni < 4; ++ni) {
                    const float lv = acc[mi][ni][rj] * INV_TEMP;
                    rs += __expf(lv);
                    if (isPos) pos[((size_t)r << 11) + cbase + ni * 16] = lv;
                }
                rsv[mi * 4 + rj] += rs;
            }
        }
        #pragma unroll
        for (int mi = 0; mi < 4; ++mi)
            #pragma unroll
            for (int ni = 0; ni < 4; ++ni)
                acc[mi][ni] = (f32x4){0.0f, 0.0f, 0.0f, 0.0f};

        cur ^= 1;
    }

    // ---- one shuffle-reduce at the end: sum over the 16 col-lanes ----
    #pragma unroll
    for (int j = 0; j < 16; ++j) {
        float v = rsv[j];
        v += __shfl_xor(v, 1);
        v += __shfl_xor(v, 2);
        v += __shfl_xor(v, 4);
        v += __shfl_xor(v, 8);
        if ((lane & 15) == 0) {
            const int r = s * 256 + w * 64 + (j >> 2) * 16 + rsub * 4 + (j & 3);
            part[((size_t)r << 6) + g] = v;    // [row][group] -> coalesced pass3 reads
        }
    }
}

// Pass 3: per-row finish. S_all = sum_g part[r][g]; N = S_all - posExpSum + 2048.
// P = sum over positives of (l - log(exp(l)+N)), excluding diagonal for class-1 rows.
__global__ __launch_bounds__(256) void pass3_kernel(
    const int* __restrict__ y, const float* __restrict__ part,
    const float* __restrict__ pos, float* __restrict__ out)
{
    __shared__ float sh[12];
    const int r = blockIdx.x;
    const int t = threadIdx.x;
    const int c = y[r & 255];
    const float4_t* row4 = (const float4_t*)(pos + ((size_t)r << 11));
    float4_t va = row4[t];
    float4_t vb = row4[t + 256];
    float l[8] = { va.x, va.y, va.z, va.w, vb.x, vb.y, vb.z, vb.w };
    float e[8];
    float eSum = 0.0f;
    #pragma unroll
    for (int i = 0; i < 8; ++i) { e[i] = __expf(l[i]); eSum += e[i]; }
    float sa = (t < NGRP) ? part[((size_t)r << 6) + t] : 0.0f;
    #pragma unroll
    for (int m = 1; m < 64; m <<= 1) {
        eSum += __shfl_xor(eSum, m);
        sa   += __shfl_xor(sa, m);
    }
    const int w = t >> 6;
    if ((t & 63) == 0) { sh[w] = eSum; sh[4 + w] = sa; }
    __syncthreads();
    const float eTot  = sh[0] + sh[1] + sh[2] + sh[3];
    const float saTot = sh[4] + sh[5] + sh[6] + sh[7];
    const float N = saTot - eTot + (float)BANK;

    float P = 0.0f;
    #pragma unroll
    for (int i = 0; i < 8; ++i) {
        const int m = (i < 4) ? (4 * t + i) : (1024 + 4 * t + (i - 4));
        const bool skip = (c == 1) && (m == r);
        if (!skip) P += l[i] - __logf(e[i] + N);
    }
    #pragma unroll
    for (int m = 1; m < 64; m <<= 1) P += __shfl_xor(P, m);
    if ((t & 63) == 0) sh[8 + w] = P;
    __syncthreads();
    if (t == 0) {
        const float Ptot = sh[8] + sh[9] + sh[10] + sh[11];
        const float denom = (c == 1) ? (float)(BANK - 1) : (float)BANK;
        atomicAdd(out, (-Ptot / denom) * (1.0f / (float)NROWS));
    }
}

extern "C" void kernel_launch(void* const* d_in, const int* in_sizes, int n_in,
                              void* d_out, int out_size, void* d_ws, size_t ws_size,
                              hipStream_t stream) {
    const float* X = (const float*)d_in[0];
    const int*   y = (const int*)d_in[1];
    const float* Q = (const float*)d_in[2];
    float* out  = (float*)d_out;
    float* pos  = (float*)d_ws;                                  // 2048*2048 f32 (16.8 MB)
    float* part = pos + (size_t)NROWS * BANK;                    // 2048*64 f32 (512 KB)
    unsigned short* Abuf = (unsigned short*)(part + (size_t)NROWS * NGRP);  // 1 MB
    unsigned short* Bbuf = Abuf + ((size_t)A_CHUNKS << 3);                  // 18.9 MB

    pass0_pack<<<dim3(TOT_CHUNKS / 256), dim3(256), 0, stream>>>(X, Q, Abuf, Bbuf, out);
    pass1_gemm<<<dim3(NSTRIP * NGRP), dim3(256), 0, stream>>>(Abuf, Bbuf, y, part, pos);
    pass3_kernel<<<dim3(NROWS), dim3(256), 0, stream>>>(y, part, pos, out);
}

// Round 7
// 118.609 us; speedup vs baseline: 1.5904x; 1.2630x over previous
//
#include <hip/hip_runtime.h>

typedef float  float4_t __attribute__((ext_vector_type(4)));
typedef unsigned int uint4_t __attribute__((ext_vector_type(4)));
typedef short  bf16x8  __attribute__((ext_vector_type(8)));
typedef float  f32x4   __attribute__((ext_vector_type(4)));

#define FEAT   256
#define BANK   2048
#define NROWS  2048       // 256 anchors * 8 views
#define BM     128
#define BN     128
#define BK     32
#define NKT    8          // FEAT / BK
#define NCT    288        // column tiles
#define INV_TEMP 10.0f
#define A_CHUNKS 65536        // 2048*256/8 chunks of 8 bf16
#define B_CHUNKS 1179648      // 36864*256/8
#define TOT_CHUNKS (A_CHUNKS + B_CHUNKS)

typedef unsigned int __attribute__((address_space(1))) guint;
typedef unsigned int __attribute__((address_space(3))) luint;

// round-to-nearest-even f32 -> bf16, two at a time packed into a uint
__device__ inline unsigned int pack_bf16x2(float lo, float hi) {
    unsigned int ulo = __builtin_bit_cast(unsigned int, lo);
    unsigned int uhi = __builtin_bit_cast(unsigned int, hi);
    unsigned int rl = 0x7FFFu + ((ulo >> 16) & 1u);
    unsigned int rh = 0x7FFFu + ((uhi >> 16) & 1u);
    return ((ulo + rl) >> 16) | ((uhi + rh) & 0xFFFF0000u);
}

// Pass 0: convert fp32 -> bf16 ONCE into MFMA fragment order for 128x32 tiles.
// Tile (rt|ct, kt) = 512 chunks of 8 bf16. chunk c in tile: rf = c>>6 (16-row
// frag), lane = c&63; row = rf*16 + (lane&15); k = (lane>>4)*8.
__global__ __launch_bounds__(256) void pass0_pack(
    const float* __restrict__ X,    // X_anchor [256][8][256]
    const float* __restrict__ Q,    // queue [19][2048][256]
    unsigned short* __restrict__ Abuf,
    unsigned short* __restrict__ Bbuf,
    float* __restrict__ out)
{
    const int cid = blockIdx.x * 256 + threadIdx.x;
    if (cid == 0) out[0] = 0.0f;
    if (cid >= TOT_CHUNKS) return;
    const int lane = cid & 63;
    const int rf   = (cid >> 6) & 7;
    const int kt   = (cid >> 9) & 7;
    const int k    = kt * BK + ((lane >> 4) << 3);
    const int rloc = (rf << 4) | (lane & 15);
    const float* src;
    unsigned short* dst;
    if (cid < A_CHUNKS) {
        const int rt = cid >> 12;                   // 0..15
        const int r  = rt * BM + rloc;              // anchor row = v*256+a
        src = X + ((size_t)((r & 255) * 8 + (r >> 8))) * FEAT + k;
        dst = Abuf + ((size_t)cid << 3);
    } else {
        const int bcid = cid - A_CHUNKS;
        const int ct  = bcid >> 12;                 // 0..287
        const int col = ct * BN + rloc;             // class 0 skipped
        src = Q + ((size_t)(BANK + col)) * FEAT + k;
        dst = Bbuf + ((size_t)bcid << 3);
    }
    float4_t v0 = *(const float4_t*)src;
    float4_t v1 = *(const float4_t*)(src + 4);
    uint4_t p = { pack_bf16x2(v0.x, v0.y), pack_bf16x2(v0.z, v0.w),
                  pack_bf16x2(v1.x, v1.y), pack_bf16x2(v1.z, v1.w) };
    *(uint4_t*)dst = p;
}

// Pass 1: 128x128 tile, 2x2 waves, BK=32 double-buffered (32 KB LDS), counted
// vmcnt(4) prefetch pipeline (never 0 mid-loop), XCD-contiguous ct bands.
//   - per-block row exp-sums -> LDS reduce -> part[ct][r]
//   - stores logit into pos[r][col&2047] when col's class == y[r&255]
__global__ __launch_bounds__(256) void pass1_gemm(
    const unsigned short* __restrict__ Abuf,
    const unsigned short* __restrict__ Bbuf,
    const int*   __restrict__ y,
    float* __restrict__ part,   // [NCT][NROWS]
    float* __restrict__ pos)    // [NROWS][BANK]
{
    __shared__ __align__(16) unsigned short lA[2][4096];   // 2 x 8 KB
    __shared__ __align__(16) unsigned short lB[2][4096];

    // XCD-contiguous: xcd = bid&7 owns ct band [xcd*36, xcd*36+36) x all 16 rt
    const int bid = blockIdx.x;
    const int xcd = bid & 7;
    const int idx = bid >> 3;              // 0..575
    const int rt  = idx / 36;              // 0..15
    const int ct  = xcd * 36 + (idx % 36); // 0..287

    const int t    = threadIdx.x;
    const int lane = t & 63;
    const int w    = t >> 6;
    const int wr   = w >> 1, wc = w & 1;   // 2x2 waves, each 64x64
    const int g    = lane >> 4;

    f32x4 acc[4][4] = {};

    auto STAGE = [&](int buf, int kt) {
        const unsigned short* Ak = Abuf + (((size_t)(rt * NKT + kt)) << 12);
        const unsigned short* Bk = Bbuf + (((size_t)(ct * NKT + kt)) << 12);
        #pragma unroll
        for (int i = 0; i < 2; ++i) {
            const int cb = (w * 2 + i) << 6;   // wave-uniform chunk base, 8 loads cover 512
            __builtin_amdgcn_global_load_lds((const guint*)(Ak + ((cb + lane) << 3)),
                                             (luint*)&lA[buf][cb << 3], 16, 0, 0);
            __builtin_amdgcn_global_load_lds((const guint*)(Bk + ((cb + lane) << 3)),
                                             (luint*)&lB[buf][cb << 3], 16, 0, 0);
        }
    };

    STAGE(0, 0);

    int cur = 0;
    #pragma unroll 1
    for (int kt = 0; kt < NKT; ++kt) {
        if (kt + 1 < NKT) {
            STAGE(cur ^ 1, kt + 1);                          // next tile stays in flight
            asm volatile("s_waitcnt vmcnt(4)" ::: "memory"); // only CURRENT tile drained
        } else {
            asm volatile("s_waitcnt vmcnt(0)" ::: "memory");
        }
        __builtin_amdgcn_s_barrier();          // all waves' stage(cur) landed
        __builtin_amdgcn_sched_barrier(0);

        bf16x8 af[4], bfv[4];
        #pragma unroll
        for (int mi = 0; mi < 4; ++mi)
            af[mi] = *(const bf16x8*)&lA[cur][((((wr << 2) | mi) << 6) | lane) << 3];
        #pragma unroll
        for (int ni = 0; ni < 4; ++ni)
            bfv[ni] = *(const bf16x8*)&lB[cur][((((wc << 2) | ni) << 6) | lane) << 3];

        __builtin_amdgcn_s_setprio(1);
        #pragma unroll
        for (int mi = 0; mi < 4; ++mi)
            #pragma unroll
            for (int ni = 0; ni < 4; ++ni)
                acc[mi][ni] = __builtin_amdgcn_mfma_f32_16x16x32_bf16(af[mi], bfv[ni], acc[mi][ni], 0, 0, 0);
        __builtin_amdgcn_s_setprio(0);

        asm volatile("s_waitcnt lgkmcnt(0)" ::: "memory");   // my ds_reads consumed
        __builtin_amdgcn_s_barrier();                        // cur free to overwrite
        __builtin_amdgcn_sched_barrier(0);
        cur ^= 1;
    }

    // ---- epilogue: logits = acc*10; exp; row-sums -> LDS reduce; store positives ----
    float* redf = (float*)lA;               // 256 floats, safe after final barrier
    const int cj = (ct >> 4) + 1;           // class of this col tile (1..18)
    const int colbase = ct * BN + wc * 64 + (lane & 15);
    #pragma unroll
    for (int mi = 0; mi < 4; ++mi) {
        #pragma unroll
        for (int rj = 0; rj < 4; ++rj) {
            const int rloc = wr * 64 + mi * 16 + g * 4 + rj;
            const int r = rt * BM + rloc;
            const bool isPos = (y[r & 255] == cj);
            float rs = 0.0f;
            #pragma unroll
            for (int ni = 0; ni < 4; ++ni) {
                const float lv = acc[mi][ni][rj] * INV_TEMP;
                rs += __expf(lv);
                if (isPos) pos[(size_t)r * BANK + ((colbase + ni * 16) & (BANK - 1))] = lv;
            }
            rs += __shfl_xor(rs, 1);
            rs += __shfl_xor(rs, 2);
            rs += __shfl_xor(rs, 4);
            rs += __shfl_xor(rs, 8);
            if ((lane & 15) == 0) redf[wc * 128 + rloc] = rs;
        }
    }
    __syncthreads();
    if (t < BM) part[(size_t)ct * NROWS + rt * BM + t] = redf[t] + redf[128 + t];
}

// Pass 3: per-row finish. S_all = sum_ct part[ct][r]; N = S_all - posExpSum + 2048.
// P = sum over positives of (l - log(exp(l)+N)), excluding diagonal for class-1 rows.
__global__ __launch_bounds__(256) void pass3_kernel(
    const int* __restrict__ y, const float* __restrict__ part,
    const float* __restrict__ pos, float* __restrict__ out)
{
    __shared__ float sh[12];
    const int r = blockIdx.x;
    const int t = threadIdx.x;
    const int c = y[r & 255];
    const float4_t* row4 = (const float4_t*)(pos + ((size_t)r << 11));
    float4_t va = row4[t];
    float4_t vb = row4[t + 256];
    float l[8] = { va.x, va.y, va.z, va.w, vb.x, vb.y, vb.z, vb.w };
    float e[8];
    float eSum = 0.0f;
    #pragma unroll
    for (int i = 0; i < 8; ++i) { e[i] = __expf(l[i]); eSum += e[i]; }
    float sa = 0.0f;
    for (int ctb = t; ctb < NCT; ctb += 256) sa += part[(size_t)ctb * NROWS + r];
    #pragma unroll
    for (int m = 1; m < 64; m <<= 1) {
        eSum += __shfl_xor(eSum, m);
        sa   += __shfl_xor(sa, m);
    }
    const int w = t >> 6;
    if ((t & 63) == 0) { sh[w] = eSum; sh[4 + w] = sa; }
    __syncthreads();
    const float eTot  = sh[0] + sh[1] + sh[2] + sh[3];
    const float saTot = sh[4] + sh[5] + sh[6] + sh[7];
    const float N = saTot - eTot + (float)BANK;

    float P = 0.0f;
    #pragma unroll
    for (int i = 0; i < 8; ++i) {
        const int m = (i < 4) ? (4 * t + i) : (1024 + 4 * t + (i - 4));
        const bool skip = (c == 1) && (m == r);
        if (!skip) P += l[i] - __logf(e[i] + N);
    }
    #pragma unroll
    for (int m = 1; m < 64; m <<= 1) P += __shfl_xor(P, m);
    if ((t & 63) == 0) sh[8 + w] = P;
    __syncthreads();
    if (t == 0) {
        const float Ptot = sh[8] + sh[9] + sh[10] + sh[11];
        const float denom = (c == 1) ? (float)(BANK - 1) : (float)BANK;
        atomicAdd(out, (-Ptot / denom) * (1.0f / (float)NROWS));
    }
}

extern "C" void kernel_launch(void* const* d_in, const int* in_sizes, int n_in,
                              void* d_out, int out_size, void* d_ws, size_t ws_size,
                              hipStream_t stream) {
    const float* X = (const float*)d_in[0];
    const int*   y = (const int*)d_in[1];
    const float* Q = (const float*)d_in[2];
    float* out  = (float*)d_out;
    float* pos  = (float*)d_ws;                                  // 2048*2048 f32 (16.8 MB)
    float* part = pos + (size_t)NROWS * BANK;                    // 288*2048 f32 (2.36 MB)
    unsigned short* Abuf = (unsigned short*)(part + (size_t)NCT * NROWS);   // 1 MB
    unsigned short* Bbuf = Abuf + ((size_t)A_CHUNKS << 3);                  // 18.9 MB

    pass0_pack<<<dim3((TOT_CHUNKS + 255) / 256), dim3(256), 0, stream>>>(X, Q, Abuf, Bbuf, out);
    pass1_gemm<<<dim3(16 * NCT), dim3(256), 0, stream>>>(Abuf, Bbuf, y, part, pos);
    pass3_kernel<<<dim3(NROWS), dim3(256), 0, stream>>>(y, part, pos, out);
}